// Round 1
// baseline (92.014 us; speedup 1.0000x reference)
//
#include <hip/hip_runtime.h>
#include <hip/hip_bf16.h>

// out[b,u] = exp(-0.5 * (|x_b|^2 - 2*x.mu + |mu_u|^2))
// x: (65536, 64) f32 row-major; mu: (64, 256) f32 row-major; out: (65536, 256) f32.
// bf16 MFMA for the cross term; |x|^2 / |mu|^2 in fp32 from original values.

typedef __attribute__((ext_vector_type(8))) short short8;   // 8 bf16 (4 VGPRs)
typedef __attribute__((ext_vector_type(4))) float floatx4;  // MFMA C/D frag

__device__ inline short f2bf_rne(float f) {
    unsigned int u = __float_as_uint(f);
    u += 0x7fffu + ((u >> 16) & 1u);   // round-to-nearest-even (no NaN in data)
    return (short)(u >> 16);
}

__global__ __launch_bounds__(256, 4) void rbf_kernel(
    const float* __restrict__ x, const float* __restrict__ mu,
    float* __restrict__ out, int nRowTiles, int gridBlocks)
{
    const int tid  = threadIdx.x;
    const int wave = tid >> 6;       // 0..3, owns u in [64*wave, 64*wave+64)
    const int lane = tid & 63;
    const int l15  = lane & 15;
    const int g    = lane >> 4;      // 0..3

    // ---- B (mu) fragments, loaded once, held in registers for whole kernel ----
    // frag layout (16x16x32 bf16): lane holds B[k = 32h + 8g + e][u0 + l15]
    short8 bfrag[4][2];
    float  msq[4];                   // -0.5 * |mu_u|^2 for col u0+l15 of tile t
    const int ubase = wave * 64;
    #pragma unroll
    for (int t = 0; t < 4; ++t) {
        const int u = ubase + t * 16 + l15;
        float sq = 0.f;
        #pragma unroll
        for (int h = 0; h < 2; ++h) {
            short8 bf;
            const int k0 = 32 * h + 8 * g;
            #pragma unroll
            for (int e = 0; e < 8; ++e) {
                float v = mu[(k0 + e) * 256 + u];
                sq += v * v;
                bf[e] = f2bf_rne(v);
            }
            bfrag[t][h] = bf;
        }
        // sum over the 4 lane-groups holding the other k's of this column
        sq += __shfl_xor(sq, 16);
        sq += __shfl_xor(sq, 32);
        msq[t] = -0.5f * sq;
    }

    // ---- grid-stride over 16-row tiles ----
    for (int rt = blockIdx.x; rt < nRowTiles; rt += gridBlocks) {
        const int b0 = rt * 16;
        // A frag: lane holds x[b0 + l15][k = 32h + 8g + e]
        const float* xr = x + (size_t)(b0 + l15) * 64 + 8 * g;
        floatx4 v0 = *(const floatx4*)(xr);
        floatx4 v1 = *(const floatx4*)(xr + 4);
        floatx4 v2 = *(const floatx4*)(xr + 32);
        floatx4 v3 = *(const floatx4*)(xr + 36);

        short8 afrag[2];
        float xsq = 0.f;
        #pragma unroll
        for (int e = 0; e < 4; ++e) {
            xsq += v0[e] * v0[e] + v1[e] * v1[e];
            xsq += v2[e] * v2[e] + v3[e] * v3[e];
            afrag[0][e]     = f2bf_rne(v0[e]);
            afrag[0][e + 4] = f2bf_rne(v1[e]);
            afrag[1][e]     = f2bf_rne(v2[e]);
            afrag[1][e + 4] = f2bf_rne(v3[e]);
        }
        // full |x_row|^2 for row b0+l15 (fp32)
        xsq += __shfl_xor(xsq, 16);
        xsq += __shfl_xor(xsq, 32);
        // epilogue lane needs rows b0 + 4g + r (C/D layout: row=4*(lane>>4)+reg)
        float xh[4];
        #pragma unroll
        for (int r = 0; r < 4; ++r)
            xh[r] = -0.5f * __shfl(xsq, 4 * g + r);

        #pragma unroll
        for (int t = 0; t < 4; ++t) {
            floatx4 acc = {0.f, 0.f, 0.f, 0.f};
            acc = __builtin_amdgcn_mfma_f32_16x16x32_bf16(afrag[0], bfrag[t][0], acc, 0, 0, 0);
            acc = __builtin_amdgcn_mfma_f32_16x16x32_bf16(afrag[1], bfrag[t][1], acc, 0, 0, 0);
            const int u = ubase + t * 16 + l15;
            #pragma unroll
            for (int r = 0; r < 4; ++r) {
                // -0.5*l2 = cross - 0.5|x|^2 - 0.5|mu|^2
                float arg = acc[r] + xh[r] + msq[t];
                out[(size_t)(b0 + 4 * g + r) * 256 + u] = __expf(arg);
            }
        }
    }
}

extern "C" void kernel_launch(void* const* d_in, const int* in_sizes, int n_in,
                              void* d_out, int out_size, void* d_ws, size_t ws_size,
                              hipStream_t stream) {
    const float* x  = (const float*)d_in[0];   // (65536, 64)
    const float* mu = (const float*)d_in[1];   // (64, 256)
    float* out = (float*)d_out;                // (65536, 256)
    const int nRowTiles = 65536 / 16;          // 4096
    const int gridBlocks = 2048;               // 2 row-tiles per block
    hipLaunchKernelGGL(rbf_kernel, dim3(gridBlocks), dim3(256), 0, stream,
                       x, mu, out, nRowTiles, gridBlocks);
}